// Round 1
// baseline (446.058 us; speedup 1.0000x reference)
//
#include <hip/hip_runtime.h>
#include <hip/hip_bf16.h>
#include <stdint.h>

// GPTQ 4-bit linear: y = x @ dequant(qweight,qzeros,scales) + bias
// x: [4,2048,4096] fp32  -> M=8192 rows
// qweight: [512, 4096] int32 (8 nibbles along K per word)
// qzeros:  [32, 512]  int32 (8 nibbles along N per word), z = nibble + 1
// scales:  [32, 4096] fp32, bias: [4096] fp32, out fp32 [8192,4096]

#define M_TOT 8192
#define N_TOT 4096
#define K_TOT 4096

#define BM 128
#define BN 128
#define BK 32

using bf16x8 = __attribute__((ext_vector_type(8))) __bf16;
using f32x4  = __attribute__((ext_vector_type(4))) float;

__device__ __forceinline__ unsigned short f2bf(float f) {
  unsigned u = __builtin_bit_cast(unsigned, f);
  u += 0x7fffu + ((u >> 16) & 1u);   // round-to-nearest-even
  return (unsigned short)(u >> 16);
}

// ---------------- x: fp32 -> bf16 ----------------
__global__ void cvt_x_kernel(const float* __restrict__ x,
                             unsigned short* __restrict__ xb, int n) {
  int stride = gridDim.x * blockDim.x * 8;
  for (int i = (blockIdx.x * blockDim.x + threadIdx.x) * 8; i < n; i += stride) {
    float4 a = *reinterpret_cast<const float4*>(x + i);
    float4 b = *reinterpret_cast<const float4*>(x + i + 4);
    unsigned short o[8] = {f2bf(a.x), f2bf(a.y), f2bf(a.z), f2bf(a.w),
                           f2bf(b.x), f2bf(b.y), f2bf(b.z), f2bf(b.w)};
    *reinterpret_cast<uint4*>(xb + i) = *reinterpret_cast<const uint4*>(o);
  }
}

// ---------------- dequant -> W^T [N][K] bf16 ----------------
// One thread per packed word: 8 consecutive k for one n -> 16B coalesced store.
__global__ void dequant_wt_kernel(const int* __restrict__ qweight,
                                  const int* __restrict__ qzeros,
                                  const float* __restrict__ scales,
                                  unsigned short* __restrict__ wt) {
  int t = blockIdx.x * blockDim.x + threadIdx.x;  // [0, N_TOT*512)
  int nn = t >> 9;         // output column n
  int kw = t & 511;        // packed word index along K (k = kw*8 + j)
  int g  = kw >> 4;        // group = (kw*8)/128
  unsigned w = (unsigned)qweight[kw * N_TOT + nn];
  float s = scales[g * N_TOT + nn];
  unsigned zw = (unsigned)qzeros[g * (N_TOT / 8) + (nn >> 3)];
  float z = (float)(((zw >> ((nn & 7) * 4)) & 15u) + 1u);  // AutoGPTQ z+1
  unsigned short o[8];
#pragma unroll
  for (int j = 0; j < 8; ++j) {
    float v = s * ((float)((w >> (4 * j)) & 15u) - z);
    o[j] = f2bf(v);
  }
  *reinterpret_cast<uint4*>(wt + (size_t)nn * K_TOT + kw * 8) =
      *reinterpret_cast<const uint4*>(o);
}

// ---------------- GEMM: C[M][N] = A[M][K] * Bt[N][K]^T + bias ----------------
// m97-verified structure: 128x128 tile, BK=32, 4 waves (2x2), each wave 64x64
// (4x4 fragments of 16x16x32 MFMA), global_load_lds width-16 staging.
__device__ __forceinline__ void gll16(const unsigned short* g, const unsigned short* l) {
  __builtin_amdgcn_global_load_lds(
      (const __attribute__((address_space(1))) void*)(uintptr_t)g,
      (__attribute__((address_space(3))) void*)(uintptr_t)l, 16, 0, 0);
}

__global__ __launch_bounds__(256) void gemm_bt_kernel(
    const unsigned short* __restrict__ A,   // [M_TOT][K_TOT] bf16
    const unsigned short* __restrict__ B,   // [N_TOT][K_TOT] bf16 (W^T)
    const float* __restrict__ bias,
    float* __restrict__ C) {
  __shared__ unsigned short As[BM * BK];  // 8 KB, linear [row][k]
  __shared__ unsigned short Bs[BN * BK];  // 8 KB

  // XCD-bijective swizzle: nwg = 2048, 2048 % 8 == 0.
  int bid = blockIdx.x;
  int swz = (bid & 7) * 256 + (bid >> 3);
  int bm = swz & 63;   // M-tile fastest -> consecutive blocks share B panel
  int bn = swz >> 6;
  int m0 = bm * BM, n0 = bn * BN;

  int t = threadIdx.x;
  int lane = t & 63, wave = t >> 6;
  int wr = wave >> 1, wc = wave & 1;
  int lr = lane & 15, kq = lane >> 4;

  // Staging: chunk c = it*256 + t covers (row = c>>2, 16B-piece = c&3).
  int row0 = t >> 2, jj = t & 3;
  const unsigned short* aSrc = A + (size_t)(m0 + row0) * K_TOT + jj * 8;
  const unsigned short* bSrc = B + (size_t)(n0 + row0) * K_TOT + jj * 8;

  f32x4 acc[4][4] = {};

  for (int k0 = 0; k0 < K_TOT; k0 += BK) {
    gll16(aSrc + k0,               &As[t * 8]);
    gll16(aSrc + (size_t)64 * K_TOT + k0, &As[2048 + t * 8]);
    gll16(bSrc + k0,               &Bs[t * 8]);
    gll16(bSrc + (size_t)64 * K_TOT + k0, &Bs[2048 + t * 8]);
    __syncthreads();  // compiler drains vmcnt(0) before s_barrier

    bf16x8 av[4], bv[4];
#pragma unroll
    for (int a = 0; a < 4; ++a)
      av[a] = *reinterpret_cast<const bf16x8*>(&As[(wr * 64 + a * 16 + lr) * BK + kq * 8]);
#pragma unroll
    for (int b = 0; b < 4; ++b)
      bv[b] = *reinterpret_cast<const bf16x8*>(&Bs[(wc * 64 + b * 16 + lr) * BK + kq * 8]);
#pragma unroll
    for (int a = 0; a < 4; ++a)
#pragma unroll
      for (int b = 0; b < 4; ++b)
        acc[a][b] = __builtin_amdgcn_mfma_f32_16x16x32_bf16(av[a], bv[b], acc[a][b], 0, 0, 0);
    __syncthreads();
  }

  // Epilogue: C/D layout col = lane&15, row = (lane>>4)*4 + reg (m89-verified).
#pragma unroll
  for (int b = 0; b < 4; ++b) {
    int ncol = n0 + wc * 64 + b * 16 + lr;
    float bz = bias[ncol];
#pragma unroll
    for (int a = 0; a < 4; ++a) {
      int mrow = m0 + wr * 64 + a * 16 + kq * 4;
#pragma unroll
      for (int r = 0; r < 4; ++r)
        C[(size_t)(mrow + r) * N_TOT + ncol] = acc[a][b][r] + bz;
    }
  }
}

extern "C" void kernel_launch(void* const* d_in, const int* in_sizes, int n_in,
                              void* d_out, int out_size, void* d_ws, size_t ws_size,
                              hipStream_t stream) {
  const float* x        = (const float*)d_in[0];
  const int*   qweight  = (const int*)d_in[1];
  const int*   qzeros   = (const int*)d_in[2];
  const float* scales   = (const float*)d_in[3];
  const float* bias     = (const float*)d_in[4];
  float* out = (float*)d_out;

  const size_t xb_bytes = (size_t)M_TOT * K_TOT * 2;   // 64 MB
  const size_t wt_bytes = (size_t)N_TOT * K_TOT * 2;   // 32 MB
  if (ws_size < xb_bytes + wt_bytes) return;  // clean-fail signal (output stays poisoned)

  unsigned short* Xb = (unsigned short*)d_ws;
  unsigned short* Wt = (unsigned short*)((char*)d_ws + xb_bytes);

  cvt_x_kernel<<<2048, 256, 0, stream>>>(x, Xb, M_TOT * K_TOT);
  dequant_wt_kernel<<<(N_TOT * 512) / 256, 256, 0, stream>>>(qweight, qzeros, scales, Wt);

  dim3 grid((M_TOT / BM) * (N_TOT / BN));  // 2048
  gemm_bt_kernel<<<grid, 256, 0, stream>>>(Xb, Wt, bias, out);
}

// Round 3
// 296.860 us; speedup vs baseline: 1.5026x; 1.5026x over previous
//
#include <hip/hip_runtime.h>
#include <hip/hip_bf16.h>
#include <stdint.h>

// GPTQ 4-bit linear: y = x @ dequant(qweight,qzeros,scales) + bias
// x: [4,2048,4096] fp32 -> M=8192 rows; qweight [512,4096] i32 (8 k-nibbles/word);
// qzeros [32,512] i32 (8 n-nibbles/word, z=nib+1); scales [32,4096] f32; out f32.

#define M_TOT 8192
#define N_TOT 4096
#define K_TOT 4096
#define NT    (K_TOT / 64)   // 64 K-tiles of BK=64

using bf16x8 = __attribute__((ext_vector_type(8))) __bf16;
using f32x4  = __attribute__((ext_vector_type(4))) float;

__device__ __forceinline__ unsigned short f2bf(float f) {
  unsigned u = __builtin_bit_cast(unsigned, f);
  u += 0x7fffu + ((u >> 16) & 1u);   // RNE
  return (unsigned short)(u >> 16);
}

// ---------------- x: fp32 -> bf16 ----------------
__global__ void cvt_x_kernel(const float* __restrict__ x,
                             unsigned short* __restrict__ xb, int n) {
  int stride = gridDim.x * blockDim.x * 8;
  for (int i = (blockIdx.x * blockDim.x + threadIdx.x) * 8; i < n; i += stride) {
    float4 a = *reinterpret_cast<const float4*>(x + i);
    float4 b = *reinterpret_cast<const float4*>(x + i + 4);
    unsigned short o[8] = {f2bf(a.x), f2bf(a.y), f2bf(a.z), f2bf(a.w),
                           f2bf(b.x), f2bf(b.y), f2bf(b.z), f2bf(b.w)};
    *reinterpret_cast<uint4*>(xb + i) = *reinterpret_cast<const uint4*>(o);
  }
}

// ---------------- dequant -> W^T [N][K] bf16 ----------------
__global__ void dequant_wt_kernel(const int* __restrict__ qweight,
                                  const int* __restrict__ qzeros,
                                  const float* __restrict__ scales,
                                  unsigned short* __restrict__ wt) {
  int t = blockIdx.x * blockDim.x + threadIdx.x;  // [0, N_TOT*512)
  int nn = t >> 9;
  int kw = t & 511;
  int g  = kw >> 4;
  unsigned w = (unsigned)qweight[kw * N_TOT + nn];
  float s = scales[g * N_TOT + nn];
  unsigned zw = (unsigned)qzeros[g * (N_TOT / 8) + (nn >> 3)];
  float z = (float)(((zw >> ((nn & 7) * 4)) & 15u) + 1u);
  unsigned short o[8];
#pragma unroll
  for (int j = 0; j < 8; ++j) {
    float v = s * ((float)((w >> (4 * j)) & 15u) - z);
    o[j] = f2bf(v);
  }
  *reinterpret_cast<uint4*>(wt + (size_t)nn * K_TOT + kw * 8) =
      *reinterpret_cast<const uint4*>(o);
}

// ---------------- 256x256 8-phase GEMM: C = A * Bt^T + bias ----------------
__device__ __forceinline__ void gll16(const unsigned short* g, const unsigned short* l) {
  __builtin_amdgcn_global_load_lds(
      (const __attribute__((address_space(1))) void*)(uintptr_t)g,
      (__attribute__((address_space(3))) void*)(uintptr_t)l, 16, 0, 0);
}

__global__ __launch_bounds__(512, 2) void gemm_8phase_kernel(
    const unsigned short* __restrict__ A,   // [M_TOT][K_TOT] bf16
    const unsigned short* __restrict__ B,   // [N_TOT][K_TOT] bf16 (W^T)
    const float* __restrict__ bias,
    float* __restrict__ C) {
  // 2 buffers x 256 rows x 64 cols bf16 each = 64 KB per operand, 128 KB total.
  __shared__ __align__(16) unsigned short As[2 * 256 * 64];
  __shared__ __align__(16) unsigned short Bs[2 * 256 * 64];

  int bid = blockIdx.x;                    // 512 blocks, 512 % 8 == 0
  int swz = (bid & 7) * 64 + (bid >> 3);   // bijective XCD swizzle (T1)
  int bm = swz & 31, bn = swz >> 5;        // 32 x 16 tiles
  int m0 = bm * 256, n0 = bn * 256;

  int t = threadIdx.x;
  int lane = t & 63;
  int wave = t >> 6;                       // 8 waves
  int wr = wave >> 2, wc = wave & 3;       // 2 (M) x 4 (N)
  int lr = lane & 15, kq = lane >> 4;

  // Staging: half-tile = 128 rows x 64 cols bf16 = 16 KB = 512thr x 2 x 16B.
  // Thread covers physical 16B slot p = t&7 of rows rowL0 and rowL0+64.
  // T2 swizzle relation: physical chunk p holds logical chunk c = p ^ (row&7);
  // gll dest stays linear, so the SOURCE is permuted: j_log = (t&7) ^ (rowL0&7).
  int rowL0 = t >> 3;                                   // 0..63
  int jlog  = ((t & 7) ^ (rowL0 & 7)) * 8;              // element offset in row
  const unsigned short* aG = A + (size_t)(m0 + rowL0) * K_TOT + jlog;
  const unsigned short* bG = B + (size_t)(n0 + rowL0) * K_TOT + jlog;

  // Swizzled read bases (byte offset within one 32KB buffer).
  // Full physical low bits = (kq*16 + s*64) ^ ((row&7)<<4); row&7 == lr&7 since
  // all row-base terms are multiples of 16. The s*64 half-select must be XORed
  // in (bit 6 collides with the XOR term when lr&7 >= 4) -- round-2 bug was
  // composing it with '+', which carried into the row field for half the lanes.
  unsigned rbA = (unsigned)((wr * 128 + lr) * 128 + ((kq * 16) ^ ((lr & 7) << 4)));
  unsigned rbB = (unsigned)((wc * 64  + lr) * 128 + ((kq * 16) ^ ((lr & 7) << 4)));

  f32x4 acc[8][4] = {};

  // STAGE one half-tile (2 x global_load_lds per thread).
  // LDS units: ushort. buffer=16384, half=8192, i-step=4096, thread slot=t*8.
#define STAGE(matG, ldsArr, tile, h)                                              \
  do {                                                                            \
    const unsigned short* _g = (matG) + (size_t)(h) * 128 * K_TOT +               \
                               (size_t)(tile) * 64;                               \
    const unsigned short* _l = (ldsArr) + ((tile) & 1) * 16384 + (h) * 8192 +     \
                               t * 8;                                             \
    gll16(_g, _l);                                                                \
    gll16(_g + (size_t)64 * K_TOT, _l + 4096);                                    \
  } while (0)

  // Prologue: tile0 fully + tile1 B halves (tile1 A halves stage in iter 0).
  STAGE(aG, As, 0, 0);
  STAGE(aG, As, 0, 1);
  STAGE(bG, Bs, 0, 0);
  STAGE(bG, Bs, 0, 1);
  STAGE(bG, Bs, 1, 0);
  STAGE(bG, Bs, 1, 1);
  asm volatile("s_waitcnt vmcnt(4)" ::: "memory");  // tile0 landed (4 = tile1 B)
  __builtin_amdgcn_s_barrier();

  for (int tt = 0; tt < NT; ++tt) {
    const char* aBuf = (const char*)As + (tt & 1) * 32768;
    const char* bBuf = (const char*)Bs + (tt & 1) * 32768;
    bf16x8 bh[4][2];   // B held in regs across the 4 phases (retires B LDS early)

#pragma unroll
    for (int q = 0; q < 4; ++q) {
      // --- ds reads for this phase (s half-select XORed: see rbA/rbB comment) ---
      if (q == 0) {
#pragma unroll
        for (int n = 0; n < 4; ++n)
#pragma unroll
          for (int s = 0; s < 2; ++s)
            bh[n][s] = *(const bf16x8*)(bBuf + ((rbB + n * 2048) ^ (s * 64)));
      }
      bf16x8 a0[2][2];
#pragma unroll
      for (int mm = 0; mm < 2; ++mm)
#pragma unroll
        for (int s = 0; s < 2; ++s)
          a0[mm][s] = *(const bf16x8*)(aBuf + ((rbA + (2 * q + mm) * 2048) ^ (s * 64)));

      // --- stage issues (T3): A halves of t+1 -> other buffer (its A retired
      // end of iter t-1); B halves of t+2 -> THIS buffer (B retired at phase 0).
      if (q == 0 && tt + 1 < NT) STAGE(aG, As, tt + 1, 0);
      if (q == 1 && tt + 1 < NT) STAGE(aG, As, tt + 1, 1);
      if (q == 1 && tt + 2 < NT) STAGE(bG, Bs, tt + 2, 0);
      if (q == 2 && tt + 2 < NT) STAGE(bG, Bs, tt + 2, 1);

      __builtin_amdgcn_s_barrier();
      __builtin_amdgcn_s_setprio(1);   // T5
#pragma unroll
      for (int s = 0; s < 2; ++s)
#pragma unroll
        for (int mm = 0; mm < 2; ++mm)
#pragma unroll
          for (int n = 0; n < 4; ++n)
            acc[2 * q + mm][n] = __builtin_amdgcn_mfma_f32_16x16x32_bf16(
                a0[mm][s], bh[n][s], acc[2 * q + mm][n], 0, 0, 0);
      __builtin_amdgcn_s_setprio(0);
      if (q == 3) {
        // T4 counted vmcnt: 4 trailing loads = (t+2).B halves. Drain at the end.
        if (tt >= NT - 2) asm volatile("s_waitcnt vmcnt(0)" ::: "memory");
        else              asm volatile("s_waitcnt vmcnt(4)" ::: "memory");
      }
      __builtin_amdgcn_s_barrier();
    }
  }
#undef STAGE

  // Epilogue: C/D layout col=lane&15, row=(lane>>4)*4+reg (round-1 verified).
#pragma unroll
  for (int n = 0; n < 4; ++n) {
    int ncol = n0 + wc * 64 + n * 16 + lr;
    float bz = bias[ncol];
#pragma unroll
    for (int m = 0; m < 8; ++m) {
      int mrow = m0 + wr * 128 + m * 16 + kq * 4;
#pragma unroll
      for (int r = 0; r < 4; ++r)
        C[(size_t)(mrow + r) * N_TOT + ncol] = acc[m][n][r] + bz;
    }
  }
}

extern "C" void kernel_launch(void* const* d_in, const int* in_sizes, int n_in,
                              void* d_out, int out_size, void* d_ws, size_t ws_size,
                              hipStream_t stream) {
  const float* x       = (const float*)d_in[0];
  const int*   qweight = (const int*)d_in[1];
  const int*   qzeros  = (const int*)d_in[2];
  const float* scales  = (const float*)d_in[3];
  const float* bias    = (const float*)d_in[4];
  float* out = (float*)d_out;

  const size_t xb_bytes = (size_t)M_TOT * K_TOT * 2;   // 64 MB
  const size_t wt_bytes = (size_t)N_TOT * K_TOT * 2;   // 32 MB
  if (ws_size < xb_bytes + wt_bytes) return;

  unsigned short* Xb = (unsigned short*)d_ws;
  unsigned short* Wt = (unsigned short*)((char*)d_ws + xb_bytes);

  cvt_x_kernel<<<2048, 256, 0, stream>>>(x, Xb, M_TOT * K_TOT);
  dequant_wt_kernel<<<(N_TOT * 512) / 256, 256, 0, stream>>>(qweight, qzeros, scales, Wt);

  dim3 grid((M_TOT / 256) * (N_TOT / 256));  // 512
  gemm_8phase_kernel<<<grid, 512, 0, stream>>>(Xb, Wt, bias, out);
}